// Round 1
// baseline (5876.051 us; speedup 1.0000x reference)
//
#include <hip/hip_runtime.h>

// EGNN layer (CamadaEquivariante): f32 baseline.
// Edge kernel: thread-per-edge, register accumulators, LDS activation column.
// Node kernel: thread-per-node.
// Scatter via global f32 atomics into d_ws (agg[N*3], cnt[N], mi[N*64]).

__device__ __forceinline__ float fast_tanh(float x) {
    // tanh(x) = 1 - 2/(e^{2x}+1); safe at +-inf.
    float e = __expf(2.0f * x);
    return 1.0f - 2.0f * __builtin_amdgcn_rcpf(e + 1.0f);
}

template<int BLK>
__global__ __launch_bounds__(BLK)
void edge_kernel(const float* __restrict__ h, const float* __restrict__ x,
                 const float* __restrict__ eattr,
                 const int* __restrict__ rows, const int* __restrict__ cols,
                 const float* __restrict__ we_w1, const float* __restrict__ we_b1,
                 const float* __restrict__ we_w2, const float* __restrict__ we_b2,
                 const float* __restrict__ wx_w1, const float* __restrict__ wx_b1,
                 const float* __restrict__ wx_w2, const float* __restrict__ wx_b2,
                 float* __restrict__ agg, float* __restrict__ cnt, float* __restrict__ mi,
                 int E)
{
    __shared__ float act[64][BLK];   // per-thread activation column, [k][tid]: 2-way bank = free
    const int tid = threadIdx.x;
    const int e = blockIdx.x * BLK + tid;
    if (e >= E) return;              // no barriers in this kernel -> safe

    const int r = rows[e];
    const int c = cols[e];

    const float d0 = x[(size_t)r*3+0] - x[(size_t)c*3+0];
    const float d1 = x[(size_t)r*3+1] - x[(size_t)c*3+1];
    const float d2 = x[(size_t)r*3+2] - x[(size_t)c*3+2];
    const float rad = d0*d0 + d1*d1 + d2*d2;

    float A[64];

    // ---- phi_e layer 1: attr[137] @ we_w1(137x64) + b1 ----
    #pragma unroll
    for (int j = 0; j < 64; j++) A[j] = we_b1[j];

    const float* hr = h + (size_t)r * 64;
    #pragma unroll 2
    for (int k = 0; k < 64; k++) {
        const float a = hr[k];
        const float* w = we_w1 + k * 64;
        #pragma unroll
        for (int j = 0; j < 64; j++) A[j] += a * w[j];
    }
    const float* hc = h + (size_t)c * 64;
    #pragma unroll 2
    for (int k = 0; k < 64; k++) {
        const float a = hc[k];
        const float* w = we_w1 + (64 + k) * 64;
        #pragma unroll
        for (int j = 0; j < 64; j++) A[j] += a * w[j];
    }
    {
        const float* w = we_w1 + 128 * 64;
        #pragma unroll
        for (int j = 0; j < 64; j++) A[j] += rad * w[j];
    }
    const float* ea = eattr + (size_t)e * 8;
    #pragma unroll
    for (int k = 0; k < 8; k++) {
        const float a = ea[k];
        const float* w = we_w1 + (129 + k) * 64;
        #pragma unroll
        for (int j = 0; j < 64; j++) A[j] += a * w[j];
    }
    // tanh -> LDS
    #pragma unroll
    for (int j = 0; j < 64; j++) act[j][tid] = fast_tanh(A[j]);

    // ---- phi_e layer 2: tanh(act @ we_w2 + b2) = m_ij ----
    float B[64];
    #pragma unroll
    for (int j = 0; j < 64; j++) B[j] = we_b2[j];
    #pragma unroll 2
    for (int k = 0; k < 64; k++) {
        const float a = act[k][tid];
        const float* w = we_w2 + k * 64;
        #pragma unroll
        for (int j = 0; j < 64; j++) B[j] += a * w[j];
    }
    #pragma unroll
    for (int j = 0; j < 64; j++) act[j][tid] = fast_tanh(B[j]);   // act = m_ij

    // ---- phi_x layer 1: tanh(m_ij @ wx_w1 + bx1) ----
    #pragma unroll
    for (int j = 0; j < 64; j++) A[j] = wx_b1[j];
    #pragma unroll 2
    for (int k = 0; k < 64; k++) {
        const float a = act[k][tid];
        const float* w = wx_w1 + k * 64;
        #pragma unroll
        for (int j = 0; j < 64; j++) A[j] += a * w[j];
    }
    // ---- phi_x layer 2: scalar ----
    float px = wx_b2[0];
    #pragma unroll
    for (int j = 0; j < 64; j++) px += fast_tanh(A[j]) * wx_w2[j];
    px = fast_tanh(px);

    // ---- scatter: agg_sum, cnt, m_i (all segmented over rows/linhas) ----
    atomicAdd(&agg[(size_t)r*3+0], d0 * px);
    atomicAdd(&agg[(size_t)r*3+1], d1 * px);
    atomicAdd(&agg[(size_t)r*3+2], d2 * px);
    atomicAdd(&cnt[r], 1.0f);
    float* mir = mi + (size_t)r * 64;
    #pragma unroll
    for (int j = 0; j < 64; j++) atomicAdd(&mir[j], act[j][tid]);
}

template<int BLK>
__global__ __launch_bounds__(BLK)
void node_kernel(const float* __restrict__ h, const float* __restrict__ x,
                 const float* __restrict__ vel,
                 const float* __restrict__ wh_w1, const float* __restrict__ wh_b1,
                 const float* __restrict__ wh_w2, const float* __restrict__ wh_b2,
                 const float* __restrict__ wv_w1, const float* __restrict__ wv_b1,
                 const float* __restrict__ wv_w2, const float* __restrict__ wv_b2,
                 const float* __restrict__ agg, const float* __restrict__ cnt,
                 const float* __restrict__ mi,
                 float* __restrict__ out_h, float* __restrict__ out_x, float* __restrict__ out_v,
                 int N)
{
    __shared__ float act[64][BLK];
    const int tid = threadIdx.x;
    const int n = blockIdx.x * BLK + tid;
    if (n >= N) return;

    const float* hn = h + (size_t)n * 64;
    const float* mn = mi + (size_t)n * 64;

    float A[64];

    // ---- phi_v: tanh(h @ wv_w1 + b1) @ wv_w2 + b2   (NO outer tanh) ----
    #pragma unroll
    for (int j = 0; j < 64; j++) A[j] = wv_b1[j];
    #pragma unroll 2
    for (int k = 0; k < 64; k++) {
        const float a = hn[k];
        const float* w = wv_w1 + k * 64;
        #pragma unroll
        for (int j = 0; j < 64; j++) A[j] += a * w[j];
    }
    float pv = wv_b2[0];
    #pragma unroll
    for (int j = 0; j < 64; j++) pv += fast_tanh(A[j]) * wv_w2[j];

    // ---- phi_h layer 1: tanh([h, m_i] @ wh_w1 + b1) ----
    #pragma unroll
    for (int j = 0; j < 64; j++) A[j] = wh_b1[j];
    #pragma unroll 2
    for (int k = 0; k < 64; k++) {
        const float a = hn[k];
        const float* w = wh_w1 + k * 64;
        #pragma unroll
        for (int j = 0; j < 64; j++) A[j] += a * w[j];
    }
    #pragma unroll 2
    for (int k = 0; k < 64; k++) {
        const float a = mn[k];
        const float* w = wh_w1 + (64 + k) * 64;
        #pragma unroll
        for (int j = 0; j < 64; j++) A[j] += a * w[j];
    }
    #pragma unroll
    for (int j = 0; j < 64; j++) act[j][tid] = fast_tanh(A[j]);

    // ---- phi_h layer 2: act @ wh_w2 + b2   (NO outer tanh) ----
    #pragma unroll
    for (int j = 0; j < 64; j++) A[j] = wh_b2[j];
    #pragma unroll 2
    for (int k = 0; k < 64; k++) {
        const float a = act[k][tid];
        const float* w = wh_w2 + k * 64;
        #pragma unroll
        for (int j = 0; j < 64; j++) A[j] += a * w[j];
    }
    float* oh = out_h + (size_t)n * 64;
    #pragma unroll
    for (int j = 0; j < 64; j++) oh[j] = A[j];

    // ---- coordinate / velocity update ----
    const float cn = cnt[n];
    const float inv = 1.0f / fmaxf(cn, 1.0f);
    #pragma unroll
    for (int d = 0; d < 3; d++) {
        const float am = agg[(size_t)n*3 + d] * inv;
        const float vn = vel[(size_t)n*3 + d] * pv + am;
        out_v[(size_t)n*3 + d] = vn;
        out_x[(size_t)n*3 + d] = x[(size_t)n*3 + d] + vn;
    }
}

extern "C" void kernel_launch(void* const* d_in, const int* in_sizes, int n_in,
                              void* d_out, int out_size, void* d_ws, size_t ws_size,
                              hipStream_t stream) {
    const float* h      = (const float*)d_in[0];
    const float* x      = (const float*)d_in[1];
    const float* vel    = (const float*)d_in[2];
    const float* eattr  = (const float*)d_in[3];
    const float* we_w1  = (const float*)d_in[4];
    const float* we_b1  = (const float*)d_in[5];
    const float* we_w2  = (const float*)d_in[6];
    const float* we_b2  = (const float*)d_in[7];
    const float* wx_w1  = (const float*)d_in[8];
    const float* wx_b1  = (const float*)d_in[9];
    const float* wx_w2  = (const float*)d_in[10];
    const float* wx_b2  = (const float*)d_in[11];
    const float* wh_w1  = (const float*)d_in[12];
    const float* wh_b1  = (const float*)d_in[13];
    const float* wh_w2  = (const float*)d_in[14];
    const float* wh_b2  = (const float*)d_in[15];
    const float* wv_w1  = (const float*)d_in[16];
    const float* wv_b1  = (const float*)d_in[17];
    const float* wv_w2  = (const float*)d_in[18];
    const float* wv_b2  = (const float*)d_in[19];
    const int*   ar     = (const int*)d_in[20];

    const int N = in_sizes[0] / 64;
    const int E = in_sizes[20] / 2;
    const int* rows = ar;
    const int* cols = ar + E;

    float* agg = (float*)d_ws;               // N*3
    float* cnt = agg + (size_t)N * 3;        // N
    float* mi  = cnt + N;                    // N*64
    hipMemsetAsync(d_ws, 0, (size_t)N * 68 * sizeof(float), stream);

    float* out_h = (float*)d_out;            // N*64
    float* out_x = out_h + (size_t)N * 64;   // N*3
    float* out_v = out_x + (size_t)N * 3;    // N*3

    constexpr int BLK = 128;
    edge_kernel<BLK><<<(E + BLK - 1) / BLK, BLK, 0, stream>>>(
        h, x, eattr, rows, cols,
        we_w1, we_b1, we_w2, we_b2,
        wx_w1, wx_b1, wx_w2, wx_b2,
        agg, cnt, mi, E);

    node_kernel<BLK><<<(N + BLK - 1) / BLK, BLK, 0, stream>>>(
        h, x, vel,
        wh_w1, wh_b1, wh_w2, wh_b2,
        wv_w1, wv_b1, wv_w2, wv_b2,
        agg, cnt, mi, out_h, out_x, out_v, N);
}

// Round 2
// 2277.833 us; speedup vs baseline: 2.5797x; 2.5797x over previous
//
#include <hip/hip_runtime.h>
#include <hip/hip_bf16.h>

// EGNN layer (CamadaEquivariante), round 2:
//  - edge kernel: thread-per-edge f32 MLP, NO atomics; streams m_ij (bf16) + trans (f32).
//  - CSR build per launch: histogram -> single-block scan -> scatter perm.
//  - agg kernel: one wave per node, gathers m_ij rows / trans via CSR (exact counts).
//  - node kernel: thread-per-node MLPs + coordinate/velocity update.
// Fallback to round-1 atomic path if ws_size too small.

__device__ __forceinline__ float fast_tanh(float x) {
    float e = __expf(2.0f * x);
    return 1.0f - 2.0f * __builtin_amdgcn_rcpf(e + 1.0f);
}

// ---------------------------------------------------------------- edge MLP ---
template<int BLK, bool STREAM>
__global__ __launch_bounds__(BLK)
void edge_kernel(const float* __restrict__ h, const float* __restrict__ x,
                 const float* __restrict__ eattr,
                 const int* __restrict__ rows, const int* __restrict__ cols,
                 const float* __restrict__ we_w1, const float* __restrict__ we_b1,
                 const float* __restrict__ we_w2, const float* __restrict__ we_b2,
                 const float* __restrict__ wx_w1, const float* __restrict__ wx_b1,
                 const float* __restrict__ wx_w2, const float* __restrict__ wx_b2,
                 __hip_bfloat16* __restrict__ mij, float* __restrict__ trans,
                 float* __restrict__ agg, float* __restrict__ cnt, float* __restrict__ mi,
                 int E)
{
    __shared__ float act[64][BLK];   // per-thread activation column, [k][tid]: 2-way bank = free
    const int tid = threadIdx.x;
    const int e = blockIdx.x * BLK + tid;
    if (e >= E) return;              // no barriers in this kernel -> safe

    const int r = rows[e];
    const int c = cols[e];

    const float d0 = x[(size_t)r*3+0] - x[(size_t)c*3+0];
    const float d1 = x[(size_t)r*3+1] - x[(size_t)c*3+1];
    const float d2 = x[(size_t)r*3+2] - x[(size_t)c*3+2];
    const float rad = d0*d0 + d1*d1 + d2*d2;

    float A[64];

    // ---- phi_e layer 1: attr[137] @ we_w1(137x64) + b1 ----
    #pragma unroll
    for (int j = 0; j < 64; j++) A[j] = we_b1[j];

    const float* hr = h + (size_t)r * 64;
    const float* hc = h + (size_t)c * 64;
    #pragma unroll 4
    for (int k = 0; k < 64; k++) {
        const float a0 = hr[k];
        const float a1 = hc[k];
        const float* w0 = we_w1 + k * 64;
        const float* w1 = we_w1 + (64 + k) * 64;
        #pragma unroll
        for (int j = 0; j < 64; j++) A[j] += a0 * w0[j] + a1 * w1[j];
    }
    {
        const float* w = we_w1 + 128 * 64;
        #pragma unroll
        for (int j = 0; j < 64; j++) A[j] += rad * w[j];
    }
    const float* ea = eattr + (size_t)e * 8;
    #pragma unroll
    for (int k = 0; k < 8; k++) {
        const float a = ea[k];
        const float* w = we_w1 + (129 + k) * 64;
        #pragma unroll
        for (int j = 0; j < 64; j++) A[j] += a * w[j];
    }
    #pragma unroll
    for (int j = 0; j < 64; j++) act[j][tid] = fast_tanh(A[j]);

    // ---- phi_e layer 2: tanh(act @ we_w2 + b2) = m_ij ----
    float B[64];
    #pragma unroll
    for (int j = 0; j < 64; j++) B[j] = we_b2[j];
    #pragma unroll 4
    for (int k = 0; k < 64; k++) {
        const float a = act[k][tid];
        const float* w = we_w2 + k * 64;
        #pragma unroll
        for (int j = 0; j < 64; j++) B[j] += a * w[j];
    }
    #pragma unroll
    for (int j = 0; j < 64; j++) act[j][tid] = fast_tanh(B[j]);   // act = m_ij

    if (STREAM) {
        // stream m_ij as bf16 (coalesced-ish 128B per thread, write-only)
        __hip_bfloat162* mo = (__hip_bfloat162*)(mij + (size_t)e * 64);
        #pragma unroll
        for (int jj = 0; jj < 32; jj++) {
            __hip_bfloat162 p;
            p.x = __float2bfloat16(act[2*jj][tid]);
            p.y = __float2bfloat16(act[2*jj+1][tid]);
            mo[jj] = p;
        }
    }

    // ---- phi_x layer 1: tanh(m_ij @ wx_w1 + bx1) ----
    #pragma unroll
    for (int j = 0; j < 64; j++) A[j] = wx_b1[j];
    #pragma unroll 4
    for (int k = 0; k < 64; k++) {
        const float a = act[k][tid];
        const float* w = wx_w1 + k * 64;
        #pragma unroll
        for (int j = 0; j < 64; j++) A[j] += a * w[j];
    }
    // ---- phi_x layer 2: scalar ----
    float px = wx_b2[0];
    #pragma unroll
    for (int j = 0; j < 64; j++) px += fast_tanh(A[j]) * wx_w2[j];
    px = fast_tanh(px);

    if (STREAM) {
        trans[(size_t)e*3+0] = d0 * px;
        trans[(size_t)e*3+1] = d1 * px;
        trans[(size_t)e*3+2] = d2 * px;
    } else {
        atomicAdd(&agg[(size_t)r*3+0], d0 * px);
        atomicAdd(&agg[(size_t)r*3+1], d1 * px);
        atomicAdd(&agg[(size_t)r*3+2], d2 * px);
        atomicAdd(&cnt[r], 1.0f);
        float* mir = mi + (size_t)r * 64;
        #pragma unroll
        for (int j = 0; j < 64; j++) atomicAdd(&mir[j], act[j][tid]);
    }
}

// ---------------------------------------------------------------- CSR build ---
__global__ void hist_kernel(const int* __restrict__ rows, int* __restrict__ hist, int E) {
    int e = blockIdx.x * blockDim.x + threadIdx.x;
    if (e < E) atomicAdd(&hist[rows[e]], 1);
}

__global__ __launch_bounds__(1024)
void scan_kernel(const int* __restrict__ hist, int* __restrict__ offs,
                 int* __restrict__ cursor, int N) {
    __shared__ int buf[1024];
    __shared__ int s_carry;
    const int tid = threadIdx.x;
    if (tid == 0) { s_carry = 0; offs[0] = 0; }
    __syncthreads();
    for (int base = 0; base < N; base += 1024) {
        const int i = base + tid;
        const int v = (i < N) ? hist[i] : 0;
        buf[tid] = v;
        __syncthreads();
        int acc = v;
        for (int off = 1; off < 1024; off <<= 1) {
            int t = (tid >= off) ? buf[tid - off] : 0;
            __syncthreads();
            acc += t;
            buf[tid] = acc;
            __syncthreads();
        }
        const int carry = s_carry;
        if (i < N) {
            offs[i + 1]  = carry + acc;      // inclusive -> offs[i+1]
            cursor[i]    = carry + acc - v;  // exclusive
        }
        __syncthreads();
        if (tid == 1023) s_carry = carry + acc;
        __syncthreads();
    }
}

__global__ void scatter_kernel(const int* __restrict__ rows, int* __restrict__ cursor,
                               int* __restrict__ perm, int E) {
    int e = blockIdx.x * blockDim.x + threadIdx.x;
    if (e < E) {
        int p = atomicAdd(&cursor[rows[e]], 1);
        perm[p] = e;
    }
}

// ------------------------------------------------------------- aggregation ---
// one wave per node: lane j sums column j of m_ij over the node's edges;
// lanes 0..2 also sum trans. Writes mi (f32 sums) and agg (MEAN already).
__global__ __launch_bounds__(256)
void agg_kernel(const __hip_bfloat16* __restrict__ mij, const float* __restrict__ trans,
                const int* __restrict__ offs, const int* __restrict__ perm,
                float* __restrict__ mi, float* __restrict__ agg, int N)
{
    const int lane = threadIdx.x & 63;
    const int n = blockIdx.x * 4 + (threadIdx.x >> 6);
    if (n >= N) return;

    int beg = __builtin_amdgcn_readfirstlane(offs[n]);
    int end = __builtin_amdgcn_readfirstlane(offs[n + 1]);

    float msum = 0.0f;
    float tsum = 0.0f;
    for (int i = beg; i < end; i++) {
        const int e = perm[i];                       // wave-uniform
        msum += __bfloat162float(mij[(size_t)e * 64 + lane]);
        if (lane < 3) tsum += trans[(size_t)e * 3 + lane];
    }
    mi[(size_t)n * 64 + lane] = msum;
    if (lane < 3) {
        const float cf = (float)(end - beg);
        agg[(size_t)n * 3 + lane] = tsum / fmaxf(cf, 1.0f);  // mean
    }
}

// -------------------------------------------------------------- node update ---
template<int BLK, bool AGG_IS_MEAN>
__global__ __launch_bounds__(BLK)
void node_kernel(const float* __restrict__ h, const float* __restrict__ x,
                 const float* __restrict__ vel,
                 const float* __restrict__ wh_w1, const float* __restrict__ wh_b1,
                 const float* __restrict__ wh_w2, const float* __restrict__ wh_b2,
                 const float* __restrict__ wv_w1, const float* __restrict__ wv_b1,
                 const float* __restrict__ wv_w2, const float* __restrict__ wv_b2,
                 const float* __restrict__ agg, const float* __restrict__ cnt,
                 const float* __restrict__ mi,
                 float* __restrict__ out_h, float* __restrict__ out_x, float* __restrict__ out_v,
                 int N)
{
    __shared__ float act[64][BLK];
    const int tid = threadIdx.x;
    const int n = blockIdx.x * BLK + tid;
    if (n >= N) return;

    const float* hn = h + (size_t)n * 64;
    const float* mn = mi + (size_t)n * 64;

    float A[64];

    // ---- phi_v: tanh(h @ wv_w1 + b1) @ wv_w2 + b2   (NO outer tanh) ----
    #pragma unroll
    for (int j = 0; j < 64; j++) A[j] = wv_b1[j];
    #pragma unroll 4
    for (int k = 0; k < 64; k++) {
        const float a = hn[k];
        const float* w = wv_w1 + k * 64;
        #pragma unroll
        for (int j = 0; j < 64; j++) A[j] += a * w[j];
    }
    float pv = wv_b2[0];
    #pragma unroll
    for (int j = 0; j < 64; j++) pv += fast_tanh(A[j]) * wv_w2[j];

    // ---- phi_h layer 1: tanh([h, m_i] @ wh_w1 + b1) ----
    #pragma unroll
    for (int j = 0; j < 64; j++) A[j] = wh_b1[j];
    #pragma unroll 4
    for (int k = 0; k < 64; k++) {
        const float a0 = hn[k];
        const float a1 = mn[k];
        const float* w0 = wh_w1 + k * 64;
        const float* w1 = wh_w1 + (64 + k) * 64;
        #pragma unroll
        for (int j = 0; j < 64; j++) A[j] += a0 * w0[j] + a1 * w1[j];
    }
    #pragma unroll
    for (int j = 0; j < 64; j++) act[j][tid] = fast_tanh(A[j]);

    // ---- phi_h layer 2: act @ wh_w2 + b2   (NO outer tanh) ----
    #pragma unroll
    for (int j = 0; j < 64; j++) A[j] = wh_b2[j];
    #pragma unroll 4
    for (int k = 0; k < 64; k++) {
        const float a = act[k][tid];
        const float* w = wh_w2 + k * 64;
        #pragma unroll
        for (int j = 0; j < 64; j++) A[j] += a * w[j];
    }
    float* oh = out_h + (size_t)n * 64;
    #pragma unroll
    for (int j = 0; j < 64; j++) oh[j] = A[j];

    // ---- coordinate / velocity update ----
    float inv = 1.0f;
    if (!AGG_IS_MEAN) inv = 1.0f / fmaxf(cnt[n], 1.0f);
    #pragma unroll
    for (int d = 0; d < 3; d++) {
        const float am = agg[(size_t)n*3 + d] * inv;
        const float vn = vel[(size_t)n*3 + d] * pv + am;
        out_v[(size_t)n*3 + d] = vn;
        out_x[(size_t)n*3 + d] = x[(size_t)n*3 + d] + vn;
    }
}

// ------------------------------------------------------------------ launch ---
extern "C" void kernel_launch(void* const* d_in, const int* in_sizes, int n_in,
                              void* d_out, int out_size, void* d_ws, size_t ws_size,
                              hipStream_t stream) {
    const float* h      = (const float*)d_in[0];
    const float* x      = (const float*)d_in[1];
    const float* vel    = (const float*)d_in[2];
    const float* eattr  = (const float*)d_in[3];
    const float* we_w1  = (const float*)d_in[4];
    const float* we_b1  = (const float*)d_in[5];
    const float* we_w2  = (const float*)d_in[6];
    const float* we_b2  = (const float*)d_in[7];
    const float* wx_w1  = (const float*)d_in[8];
    const float* wx_b1  = (const float*)d_in[9];
    const float* wx_w2  = (const float*)d_in[10];
    const float* wx_b2  = (const float*)d_in[11];
    const float* wh_w1  = (const float*)d_in[12];
    const float* wh_b1  = (const float*)d_in[13];
    const float* wh_w2  = (const float*)d_in[14];
    const float* wh_b2  = (const float*)d_in[15];
    const float* wv_w1  = (const float*)d_in[16];
    const float* wv_b1  = (const float*)d_in[17];
    const float* wv_w2  = (const float*)d_in[18];
    const float* wv_b2  = (const float*)d_in[19];
    const int*   ar     = (const int*)d_in[20];

    const int N = in_sizes[0] / 64;
    const int E = in_sizes[20] / 2;
    const int* rows = ar;
    const int* cols = ar + E;

    float* out_h = (float*)d_out;            // N*64
    float* out_x = out_h + (size_t)N * 64;   // N*3
    float* out_v = out_x + (size_t)N * 3;    // N*3

    constexpr int BLK = 128;

    // --- workspace layout (streaming path) ---
    char* p = (char*)d_ws;
    __hip_bfloat16* mij = (__hip_bfloat16*)p;  p += (size_t)E * 64 * sizeof(__hip_bfloat16);
    float* trans = (float*)p;                  p += (size_t)E * 3 * sizeof(float);
    float* mi    = (float*)p;                  p += (size_t)N * 64 * sizeof(float);
    float* agg   = (float*)p;                  p += (size_t)N * 3 * sizeof(float);
    int*   offs  = (int*)p;                    p += (size_t)(N + 1) * sizeof(int);
    int*   cursor= (int*)p;                    p += (size_t)N * sizeof(int);
    int*   hist  = (int*)p;                    p += (size_t)N * sizeof(int);
    int*   perm  = (int*)p;                    p += (size_t)E * sizeof(int);
    const size_t needed = (size_t)(p - (char*)d_ws);

    if (ws_size >= needed) {
        // --- streaming + CSR path ---
        hipMemsetAsync(hist, 0, (size_t)N * sizeof(int), stream);
        hist_kernel<<<(E + 255) / 256, 256, 0, stream>>>(rows, hist, E);
        scan_kernel<<<1, 1024, 0, stream>>>(hist, offs, cursor, N);
        scatter_kernel<<<(E + 255) / 256, 256, 0, stream>>>(rows, cursor, perm, E);

        edge_kernel<BLK, true><<<(E + BLK - 1) / BLK, BLK, 0, stream>>>(
            h, x, eattr, rows, cols,
            we_w1, we_b1, we_w2, we_b2,
            wx_w1, wx_b1, wx_w2, wx_b2,
            mij, trans, nullptr, nullptr, nullptr, E);

        agg_kernel<<<(N + 3) / 4, 256, 0, stream>>>(mij, trans, offs, perm, mi, agg, N);

        node_kernel<BLK, true><<<(N + BLK - 1) / BLK, BLK, 0, stream>>>(
            h, x, vel,
            wh_w1, wh_b1, wh_w2, wh_b2,
            wv_w1, wv_b1, wv_w2, wv_b2,
            agg, nullptr, mi, out_h, out_x, out_v, N);
    } else {
        // --- fallback: round-1 atomic path ---
        float* agg2 = (float*)d_ws;               // N*3
        float* cnt2 = agg2 + (size_t)N * 3;       // N
        float* mi2  = cnt2 + N;                   // N*64
        hipMemsetAsync(d_ws, 0, (size_t)N * 68 * sizeof(float), stream);

        edge_kernel<BLK, false><<<(E + BLK - 1) / BLK, BLK, 0, stream>>>(
            h, x, eattr, rows, cols,
            we_w1, we_b1, we_w2, we_b2,
            wx_w1, wx_b1, wx_w2, wx_b2,
            nullptr, nullptr, agg2, cnt2, mi2, E);

        node_kernel<BLK, false><<<(N + BLK - 1) / BLK, BLK, 0, stream>>>(
            h, x, vel,
            wh_w1, wh_b1, wh_w2, wh_b2,
            wv_w1, wv_b1, wv_w2, wv_b2,
            agg2, cnt2, mi2, out_h, out_x, out_v, N);
    }
}